// Round 6
// baseline (2300.029 us; speedup 1.0000x reference)
//
#include <hip/hip_runtime.h>

#define IN_F 256
#define OUT_F 64
#define BKT_BITS 8           // 256 nodes per bucket
#define BKT_NODES 256
#define BKT_CAP 5120         // fixed bucket capacity; mean 4096, sigma ~64 -> +16 sigma
#define CHUNK 2048           // edges per block for binning pass (782 blocks)
#define SRC_BITS 18          // N < 262144
#define SRC_MASK 0x3FFFF

typedef __attribute__((ext_vector_type(8))) short short8;    // 8 bf16 (4 VGPRs) — MFMA A/B frag
typedef __attribute__((ext_vector_type(4))) float floatx4;   // MFMA C/D frag

static __device__ __forceinline__ short f2bf_rne(float f) {
    unsigned u = __float_as_uint(f);
    unsigned r = (u + 0x7fffu + ((u >> 16) & 1u)) >> 16;  // round-nearest-even
    return (short)r;
}
static __device__ __forceinline__ float bf2f(short s) {
    return __uint_as_float(((unsigned)(unsigned short)s) << 16);
}

// ---------------- utility ----------------
__global__ void zero_kernel(int* __restrict__ p, int n) {
    int i = blockIdx.x * blockDim.x + threadIdx.x;
    if (i < n) p[i] = 0;
}

// ---------------- bin edges into fixed-capacity dst-buckets ----------------
// Block-local LDS hist -> one global atomic reservation per (block,bucket) ->
// short contiguous runs per region. bkt_cnt ends as per-bucket totals.
// binned[bkt*BKT_CAP + i].x = (dst_offset_in_bucket << SRC_BITS) | src, .y = w bits.
__global__ __launch_bounds__(256) void bin_kernel(const int* __restrict__ src,
                                                  const int* __restrict__ dst,
                                                  const float* __restrict__ w,
                                                  int* __restrict__ bkt_cnt,
                                                  int2* __restrict__ binned, int E, int nbkt) {
    __shared__ int h[512];
    int t = threadIdx.x;
    h[t] = 0;
    h[t + 256] = 0;
    __syncthreads();
    int base = blockIdx.x * CHUNK;
    int d[CHUNK / 256];
#pragma unroll
    for (int j = 0; j < CHUNK / 256; ++j) {
        int e = base + j * 256 + t;
        d[j] = (e < E) ? dst[e] : -1;
        if (d[j] >= 0) atomicAdd(&h[d[j] >> BKT_BITS], 1);
    }
    __syncthreads();
#pragma unroll
    for (int i = 0; i < 2; ++i) {
        int s = t + i * 256;  // each thread owns its 2 slots: no race on read->write
        int c = h[s];
        h[s] = (s < nbkt && c) ? atomicAdd(&bkt_cnt[s], c) : 0;
    }
    __syncthreads();
#pragma unroll
    for (int j = 0; j < CHUNK / 256; ++j) {
        int e = base + j * 256 + t;
        if (e < E) {
            int dd = d[j];
            int bb = dd >> BKT_BITS;
            int pos = atomicAdd(&h[bb], 1);
            binned[(size_t)bb * BKT_CAP + pos] =
                make_int2(((dd & (BKT_NODES - 1)) << SRC_BITS) | src[e], __float_as_int(w[e]));
        }
    }
}

// ---------------- W -> bf16 hi/lo MFMA B-fragments ----------------
__global__ void wfrag_kernel(const float* __restrict__ W,
                             short* __restrict__ bh, short* __restrict__ bl) {
    int t = blockIdx.x * blockDim.x + threadIdx.x;
    if (t >= 32 * 64) return;
    int combo = t >> 6;
    int lane = t & 63;
    int s = combo >> 2;
    int tO = combo & 3;
    int n = 16 * tO + (lane & 15);
    int k0 = 32 * s + (lane >> 4) * 8;
    const float* src = W + (size_t)n * IN_F + k0;
    short* dh = bh + (size_t)t * 8;
    short* dl = bl + (size_t)t * 8;
#pragma unroll
    for (int j = 0; j < 8; ++j) {
        float v = src[j];
        short h = f2bf_rne(v);
        dh[j] = h;
        dl[j] = f2bf_rne(v - bf2f(h));
    }
}

// ---------------- GEMM via MFMA bf16x3 ----------------
__global__ __launch_bounds__(256) void gemm_kernel(const float* __restrict__ x,
                                                   const short8* __restrict__ bh,
                                                   const short8* __restrict__ bl,
                                                   const float* __restrict__ b,
                                                   float* __restrict__ out, int N) {
    int lane = threadIdx.x & 63;
    int wid = threadIdx.x >> 6;
    int node0 = blockIdx.x * 64 + wid * 16;
    if (node0 >= N) return;
    if (node0 + 16 > N) node0 = N - 16;
    int m = lane & 15;
    int q = lane >> 4;

    const float* xrow = x + (size_t)(node0 + m) * IN_F + q * 8;

    floatx4 acc[4];
#pragma unroll
    for (int tO = 0; tO < 4; ++tO) acc[tO] = (floatx4){0.f, 0.f, 0.f, 0.f};

#pragma unroll
    for (int s = 0; s < 8; ++s) {
        float4 v0 = *(const float4*)(xrow + s * 32);
        float4 v1 = *(const float4*)(xrow + s * 32 + 4);
        float vv[8] = {v0.x, v0.y, v0.z, v0.w, v1.x, v1.y, v1.z, v1.w};
        short8 ah, al;
#pragma unroll
        for (int j = 0; j < 8; ++j) {
            short h = f2bf_rne(vv[j]);
            ah[j] = h;
            al[j] = f2bf_rne(vv[j] - bf2f(h));
        }
#pragma unroll
        for (int tO = 0; tO < 4; ++tO) {
            short8 wh = bh[(s * 4 + tO) * 64 + lane];
            short8 wl = bl[(s * 4 + tO) * 64 + lane];
            acc[tO] = __builtin_amdgcn_mfma_f32_16x16x32_bf16(ah, wh, acc[tO], 0, 0, 0);
            acc[tO] = __builtin_amdgcn_mfma_f32_16x16x32_bf16(al, wh, acc[tO], 0, 0, 0);
            acc[tO] = __builtin_amdgcn_mfma_f32_16x16x32_bf16(ah, wl, acc[tO], 0, 0, 0);
        }
    }

#pragma unroll
    for (int tO = 0; tO < 4; ++tO) {
        float bias = b[16 * tO + m];
#pragma unroll
        for (int r = 0; r < 4; ++r) {
            out[(size_t)(node0 + q * 4 + r) * OUT_F + 16 * tO + m] = acc[tO][r] + bias;
        }
    }
}

// ---------------- SpMM over buckets, no CSR ----------------
// Block = bucket (256 nodes), LDS fp32 accumulator 256x64 = 64 KB. Wave = 64 lanes,
// lane = feature. Each wave takes a contiguous chunk of the bucket's binned edges:
// gather in[src][lane], ds_add_f32 into acc[dstoff*64+lane] (lane-distinct banks,
// conflict-free; contention only on simultaneous same-dst edges across waves — rare).
__global__ __launch_bounds__(512) void spmm_bucket_kernel(const int2* __restrict__ binned,
                                                          const int* __restrict__ bkt_cnt,
                                                          const float* __restrict__ in,
                                                          float* __restrict__ out, int N) {
    __shared__ float acc[BKT_NODES * OUT_F];  // 64 KB
    int t = threadIdx.x;
    int b = blockIdx.x;
    float4* a4 = (float4*)acc;
    for (int i = t; i < BKT_NODES * OUT_F / 4; i += 512) a4[i] = make_float4(0.f, 0.f, 0.f, 0.f);
    __syncthreads();

    int cntb = bkt_cnt[b];
    const int2* es = binned + (size_t)b * BKT_CAP;
    int wid = t >> 6;
    int lane = t & 63;
    int per = (cntb + 7) >> 3;  // edges per wave (8 waves)
    int beg = wid * per;
    int end = beg + per;
    if (end > cntb) end = cntb;

    int e = beg;
    for (; e + 8 <= end; e += 8) {
        int2 m[8];
        float v[8];
#pragma unroll
        for (int j = 0; j < 8; ++j) m[j] = es[e + j];
#pragma unroll
        for (int j = 0; j < 8; ++j) v[j] = in[(size_t)(m[j].x & SRC_MASK) * OUT_F + lane];
#pragma unroll
        for (int j = 0; j < 8; ++j)
            unsafeAtomicAdd(&acc[(m[j].x >> SRC_BITS) * OUT_F + lane],
                            __int_as_float(m[j].y) * v[j]);
    }
    for (; e < end; ++e) {
        int2 m = es[e];
        float v = in[(size_t)(m.x & SRC_MASK) * OUT_F + lane];
        unsafeAtomicAdd(&acc[(m.x >> SRC_BITS) * OUT_F + lane], __int_as_float(m.y) * v);
    }
    __syncthreads();

    int node0 = b << BKT_BITS;
    float4* o4 = (float4*)out;
    for (int i = t; i < BKT_NODES * OUT_F / 4; i += 512) {
        int node = node0 + (i >> 4);
        if (node < N) o4[(size_t)node * (OUT_F / 4) + (i & 15)] = a4[i];
    }
}

// ---------------- launch ----------------
extern "C" void kernel_launch(void* const* d_in, const int* in_sizes, int n_in,
                              void* d_out, int out_size, void* d_ws, size_t ws_size,
                              hipStream_t stream) {
    const float* x = (const float*)d_in[0];
    const float* W = (const float*)d_in[1];
    const float* b = (const float*)d_in[2];
    const int* esrc = (const int*)d_in[3];
    const int* edst = (const int*)d_in[4];
    const float* ew = (const float*)d_in[5];
    float* out = (float*)d_out;

    int N = in_sizes[0] / IN_F;
    int E = in_sizes[3];
    int nbkt = (N + BKT_NODES - 1) >> BKT_BITS;   // 391 for N=100000 (must be <= 512)

    char* ws = (char*)d_ws;
    size_t off = 0;
    float* buf0 = (float*)(ws + off);    off += (size_t)N * OUT_F * sizeof(float);
    int2* binned = (int2*)(ws + off);    off += (size_t)nbkt * BKT_CAP * sizeof(int2);
    int* bkt_cnt = (int*)(ws + off);     off += 1024 * sizeof(int);
    short* bh = (short*)(ws + off);      off += 32 * 64 * 8 * sizeof(short);
    short* bl = (short*)(ws + off);      off += 32 * 64 * 8 * sizeof(short);
    (void)ws_size; (void)n_in; (void)out_size;

    int nb_chunk = (E + CHUNK - 1) / CHUNK;

    // bucket-grouped edge build: 2 kernels (no CSR needed)
    zero_kernel<<<1, 512, 0, stream>>>(bkt_cnt, nbkt);
    bin_kernel<<<nb_chunk, 256, 0, stream>>>(esrc, edst, ew, bkt_cnt, binned, E, nbkt);

    // projection
    wfrag_kernel<<<8, 256, 0, stream>>>(W, bh, bl);
    gemm_kernel<<<(N + 63) / 64, 256, 0, stream>>>(x, (const short8*)bh, (const short8*)bl,
                                                   b, buf0, N);

    // 3 hops
    spmm_bucket_kernel<<<nbkt, 512, 0, stream>>>(binned, bkt_cnt, buf0, out, N);
    spmm_bucket_kernel<<<nbkt, 512, 0, stream>>>(binned, bkt_cnt, out, buf0, N);
    spmm_bucket_kernel<<<nbkt, 512, 0, stream>>>(binned, bkt_cnt, buf0, out, N);
}